// Round 17
// baseline (68.831 us; speedup 1.0000x reference)
//
#include <hip/hip_runtime.h>

#define BB 4
#define NN 8192
#define RI 8                   // rows per thread
#define THREADS 256
#define ROWB (THREADS * RI)    // 2048 rows per block
#define PB (NN / ROWB)         // 4 row-panels
#define COLB 256               // opponent cols per block (staged once)
#define NCB (NN / COLB)        // 32 col-chunks

__device__ inline float max3f(float a, float b, float c) {
    float d;
    asm("v_max3_f32 %0, %1, %2, %3" : "=v"(d) : "v"(a), "v"(b), "v"(c));
    return d;
}

__global__ void cd_init_kernel(unsigned int* mins, int n) {
    int i = blockIdx.x * blockDim.x + threadIdx.x;
    if (i < n) mins[i] = 0x7F800000u;  // +inf
}

// Row-only fold, one kernel instance per direction (dir in grid).
// u = p.q + wq (+wp at end) = -0.5 d^2 ; row-min d^2 <-> row-max u.
__global__ __launch_bounds__(THREADS) void cd_row_kernel(
    const float* __restrict__ pred, const float* __restrict__ gt,
    const float* __restrict__ coords, unsigned int* __restrict__ mins)
{
    __shared__ float4 s4[COLB];   // (x, y, z, wq=-0.5|q|^2)

    int bid = blockIdx.x;
    int cb  = bid & (NCB - 1);
    int pb  = (bid >> 5) & (PB - 1);
    int b   = (bid >> 7) & 3;
    int dir = bid >> 9;           // 0: rows=gt -> min1 ; 1: rows=pred -> min2

    const float* cbase = coords + b * 3 * NN;
    const float* obase = (dir ? pred : gt) + b * 3 * NN;   // own rows
    const float* qbase = (dir ? gt : pred) + b * 3 * NN;   // opponent cols

    int tid = threadIdx.x;

    // stage COLB cols (THREADS == COLB: one col per thread)
    {
        int n = cb * COLB + tid;
        float x = cbase[0 * NN + n] + qbase[0 * NN + n];
        float y = cbase[1 * NN + n] + qbase[1 * NN + n];
        float z = cbase[2 * NN + n] + qbase[2 * NN + n];
        float w = -0.5f * fmaf(x, x, fmaf(y, y, z * z));
        s4[tid] = make_float4(x, y, z, w);
    }

    // rows into registers (explicit scalars, r8-verified codegen style)
    int r0 = pb * ROWB;
    float px0,px1,px2,px3,px4,px5,px6,px7;
    float py0,py1,py2,py3,py4,py5,py6,py7;
    float pz0,pz1,pz2,pz3,pz4,pz5,pz6,pz7;
    float wp0,wp1,wp2,wp3,wp4,wp5,wp6,wp7;
    float rm0,rm1,rm2,rm3,rm4,rm5,rm6,rm7;
#define LOADROW(i) { int n = r0 + tid + (i) * THREADS;                    \
    float x = cbase[0*NN+n] + obase[0*NN+n];                              \
    float y = cbase[1*NN+n] + obase[1*NN+n];                              \
    float z = cbase[2*NN+n] + obase[2*NN+n];                              \
    px##i = x; py##i = y; pz##i = z;                                      \
    wp##i = -0.5f * fmaf(x, x, fmaf(y, y, z * z));                        \
    rm##i = -3.0e38f; }
    LOADROW(0) LOADROW(1) LOADROW(2) LOADROW(3)
    LOADROW(4) LOADROW(5) LOADROW(6) LOADROW(7)
#undef LOADROW

    __syncthreads();

    // uniform broadcast scan: 2 cols per BODY, next pair prefetched
#define BODY(QA, QB) {                                                     \
    float ta0,ta1,ta2,ta3,ta4,ta5,ta6,ta7;                                 \
    float tb0,tb1,tb2,tb3,tb4,tb5,tb6,tb7;                                 \
    ta0=fmaf(px0,(QA).x,(QA).w); ta1=fmaf(px1,(QA).x,(QA).w);              \
    ta2=fmaf(px2,(QA).x,(QA).w); ta3=fmaf(px3,(QA).x,(QA).w);              \
    ta4=fmaf(px4,(QA).x,(QA).w); ta5=fmaf(px5,(QA).x,(QA).w);              \
    ta6=fmaf(px6,(QA).x,(QA).w); ta7=fmaf(px7,(QA).x,(QA).w);              \
    ta0=fmaf(py0,(QA).y,ta0); ta1=fmaf(py1,(QA).y,ta1);                    \
    ta2=fmaf(py2,(QA).y,ta2); ta3=fmaf(py3,(QA).y,ta3);                    \
    ta4=fmaf(py4,(QA).y,ta4); ta5=fmaf(py5,(QA).y,ta5);                    \
    ta6=fmaf(py6,(QA).y,ta6); ta7=fmaf(py7,(QA).y,ta7);                    \
    ta0=fmaf(pz0,(QA).z,ta0); ta1=fmaf(pz1,(QA).z,ta1);                    \
    ta2=fmaf(pz2,(QA).z,ta2); ta3=fmaf(pz3,(QA).z,ta3);                    \
    ta4=fmaf(pz4,(QA).z,ta4); ta5=fmaf(pz5,(QA).z,ta5);                    \
    ta6=fmaf(pz6,(QA).z,ta6); ta7=fmaf(pz7,(QA).z,ta7);                    \
    tb0=fmaf(px0,(QB).x,(QB).w); tb1=fmaf(px1,(QB).x,(QB).w);              \
    tb2=fmaf(px2,(QB).x,(QB).w); tb3=fmaf(px3,(QB).x,(QB).w);              \
    tb4=fmaf(px4,(QB).x,(QB).w); tb5=fmaf(px5,(QB).x,(QB).w);              \
    tb6=fmaf(px6,(QB).x,(QB).w); tb7=fmaf(px7,(QB).x,(QB).w);              \
    tb0=fmaf(py0,(QB).y,tb0); tb1=fmaf(py1,(QB).y,tb1);                    \
    tb2=fmaf(py2,(QB).y,tb2); tb3=fmaf(py3,(QB).y,tb3);                    \
    tb4=fmaf(py4,(QB).y,tb4); tb5=fmaf(py5,(QB).y,tb5);                    \
    tb6=fmaf(py6,(QB).y,tb6); tb7=fmaf(py7,(QB).y,tb7);                    \
    tb0=fmaf(pz0,(QB).z,tb0); tb1=fmaf(pz1,(QB).z,tb1);                    \
    tb2=fmaf(pz2,(QB).z,tb2); tb3=fmaf(pz3,(QB).z,tb3);                    \
    tb4=fmaf(pz4,(QB).z,tb4); tb5=fmaf(pz5,(QB).z,tb5);                    \
    tb6=fmaf(pz6,(QB).z,tb6); tb7=fmaf(pz7,(QB).z,tb7);                    \
    rm0=max3f(rm0,ta0,tb0); rm1=max3f(rm1,ta1,tb1);                        \
    rm2=max3f(rm2,ta2,tb2); rm3=max3f(rm3,ta3,tb3);                        \
    rm4=max3f(rm4,ta4,tb4); rm5=max3f(rm5,ta5,tb5);                        \
    rm6=max3f(rm6,ta6,tb6); rm7=max3f(rm7,ta7,tb7);                        \
}

    {
        float4 a0 = s4[0], b0 = s4[1];
        for (int k = 0; k < COLB; k += 4) {
            float4 a1 = s4[(k + 2) & (COLB - 1)], b1 = s4[(k + 3) & (COLB - 1)];
            BODY(a0, b0);
            a0 = s4[(k + 4) & (COLB - 1)]; b0 = s4[(k + 5) & (COLB - 1)];
            BODY(a1, b1);
        }
    }
#undef BODY

    // epilogue: d^2 = -2*(rm+wp), clamp >= 0 ; global fold across 32 col-chunks
    unsigned int* minout = mins + (dir ? 32768 : 0) + b * NN;
#define ROWEP(i) { float d = fmaxf(-2.0f * (rm##i + wp##i), 0.0f);         \
    atomicMin(&minout[r0 + tid + (i) * THREADS], __float_as_uint(d)); }
    ROWEP(0) ROWEP(1) ROWEP(2) ROWEP(3) ROWEP(4) ROWEP(5) ROWEP(6) ROWEP(7)
#undef ROWEP
}

__global__ __launch_bounds__(1024) void cd_reduce_kernel(const unsigned int* __restrict__ mins,
                                                         float* __restrict__ out)
{
    float s = 0.0f;
#pragma unroll
    for (int k = 0; k < 2 * BB * NN / 1024; ++k)
        s += __uint_as_float(mins[threadIdx.x + k * 1024]);
#pragma unroll
    for (int off = 32; off > 0; off >>= 1)
        s += __shfl_down(s, off, 64);
    __shared__ float wsum[16];
    int wave = threadIdx.x >> 6;
    if ((threadIdx.x & 63) == 0) wsum[wave] = s;
    __syncthreads();
    if (threadIdx.x == 0) {
        float t = 0.0f;
#pragma unroll
        for (int w = 0; w < 16; ++w) t += wsum[w];
        out[0] = t / (float)BB;
    }
}

extern "C" void kernel_launch(void* const* d_in, const int* in_sizes, int n_in,
                              void* d_out, int out_size, void* d_ws, size_t ws_size,
                              hipStream_t stream) {
    const float* pred   = (const float*)d_in[0];
    const float* gt     = (const float*)d_in[1];
    const float* coords = (const float*)d_in[2];
    float* out = (float*)d_out;

    unsigned int* mins = (unsigned int*)d_ws;   // min1[32768] then min2[32768]
    int total_mins = 2 * BB * NN;               // 65536

    hipLaunchKernelGGL(cd_init_kernel, dim3(total_mins / 256), dim3(256), 0, stream,
                       mins, total_mins);

    int nblocks = 2 * BB * PB * NCB;            // 1024
    hipLaunchKernelGGL(cd_row_kernel, dim3(nblocks), dim3(THREADS), 0, stream,
                       pred, gt, coords, mins);

    hipLaunchKernelGGL(cd_reduce_kernel, dim3(1), dim3(1024), 0, stream, mins, out);
}